// Round 3
// baseline (365.464 us; speedup 1.0000x reference)
//
#include <hip/hip_runtime.h>

#define NN 100000
#define NE 1600000
#define C 32

// ---------------- kernels ----------------

// zero acc, set deg=1 (self-loop)
__global__ void k_init(float* __restrict__ acc, float* __restrict__ deg) {
    int i = blockIdx.x * blockDim.x + threadIdx.x;
    if (i < NN * C) acc[i] = 0.0f;
    if (i < NN) deg[i] = 1.0f;
}

__global__ void k_count(const int* __restrict__ ei, float* __restrict__ deg) {
    int e = blockIdx.x * blockDim.x + threadIdx.x;
    if (e < NE) atomicAdd(&deg[ei[NE + e]], 1.0f);
}

__global__ void k_dinv(float* __restrict__ deg) {
    int i = blockIdx.x * blockDim.x + threadIdx.x;
    if (i < NN) deg[i] = rsqrtf(deg[i]);  // deg >= 1 always
}

// h = x @ W^T (stored f32 into d_out as scratch);
// acc = b + dinv^2 * h  (self-loop contribution)
__global__ void k_linear(const float* __restrict__ x,
                         const float* __restrict__ W,
                         const float* __restrict__ b,
                         const float* __restrict__ dinv,
                         float* __restrict__ h,
                         float* __restrict__ acc) {
    __shared__ float Ws[C][C + 1];
    __shared__ float xs[8][C];
    int t = threadIdx.x;            // 0..255
    for (int i = t; i < C * C; i += 256)
        Ws[i / C][i % C] = W[i];

    int node0 = blockIdx.x * 8;
    int lnode = t >> 5;             // 0..7
    int cout  = t & 31;
    int node  = node0 + lnode;
    {
        int idx = node0 * C + t;    // coalesced f32 load of 8 rows
        xs[lnode][cout] = (idx < NN * C) ? x[idx] : 0.0f;
    }
    __syncthreads();
    if (node < NN) {
        float s = 0.0f;
#pragma unroll
        for (int k = 0; k < C; ++k) s += xs[lnode][k] * Ws[cout][k];
        float d = dinv[node];
        h[node * C + cout]   = s;
        acc[node * C + cout] = b[cout] + d * d * s;
    }
}

// one thread per (edge, channel); 32 lanes cover one edge's channels
__global__ void k_scatter(const int* __restrict__ ei,
                          const float* __restrict__ dinv,
                          const float* __restrict__ h,
                          float* __restrict__ acc) {
    int gid = blockIdx.x * blockDim.x + threadIdx.x;
    int e = gid >> 5;
    int c = gid & 31;
    if (e < NE) {
        int r   = ei[e];
        int col = ei[NE + e];
        float v = h[r * C + c] * dinv[r] * dinv[col];
        atomicAdd(&acc[col * C + c], v);
    }
}

__global__ void k_store(const float* __restrict__ acc, float* __restrict__ out) {
    int i = blockIdx.x * blockDim.x + threadIdx.x;
    if (i < NN * C) out[i] = acc[i];
}

// ---------------- launch ----------------

extern "C" void kernel_launch(void* const* d_in, const int* in_sizes, int n_in,
                              void* d_out, int out_size, void* d_ws, size_t ws_size,
                              hipStream_t stream) {
    const float* x  = (const float*)d_in[0];
    const int*   ei = (const int*)d_in[1];
    const float* W  = (const float*)d_in[2];
    const float* b  = (const float*)d_in[3];
    float* out = (float*)d_out;

    // workspace: acc (NN*C f32 = 12.8MB) + deg/dinv (NN f32 = 0.4MB)
    float* acc = (float*)d_ws;
    float* deg = acc + NN * C;
    // h (f32, NN*C) lives in d_out until the final store overwrites it
    float* h = out;

    k_init<<<(NN * C + 255) / 256, 256, 0, stream>>>(acc, deg);
    k_count<<<(NE + 255) / 256, 256, 0, stream>>>(ei, deg);
    k_dinv<<<(NN + 255) / 256, 256, 0, stream>>>(deg);
    k_linear<<<(NN + 7) / 8, 256, 0, stream>>>(x, W, b, deg, h, acc);
    k_scatter<<<(NE * C + 255) / 256, 256, 0, stream>>>(ei, deg, h, acc);
    k_store<<<(NN * C + 255) / 256, 256, 0, stream>>>(acc, out);
}